// Round 8
// baseline (375.527 us; speedup 1.0000x reference)
//
#include <hip/hip_runtime.h>
#include <hip/hip_fp16.h>

#define EPS 1e-5f

typedef _Float16 f16x8 __attribute__((ext_vector_type(8)));
typedef float f32x4 __attribute__((ext_vector_type(4)));

// ---- ws layout (halfs): 155,348,992 B ----
#define WFH_OFF 0ull
#define W2P_OFF 6195200ull          // [kk 18][co 64][kl 32]
#define W3P_OFF 6232064ull          // [cp 2][kk 18][co 64][kl 32]
#define H3_OFF  6305792ull          // 1152 x 61952, per patch [co 128][pix 484]

// ---------------- prep ----------------
__global__ __launch_bounds__(256)
void k_prep(const float* __restrict__ w2, const float* __restrict__ w3,
            const float* __restrict__ wf, __half* __restrict__ ws)
{
    const int i = blockIdx.x * 256 + threadIdx.x;
    if (i < 1548800) {                        // wfh: vectorized linear cast
        const float4 f = *reinterpret_cast<const float4*>(wf + (size_t)i * 4);
        __half2 h0 = __floats2half2_rn(f.x, f.y);
        __half2 h1 = __floats2half2_rn(f.z, f.w);
        *reinterpret_cast<uint2*>(ws + WFH_OFF + (size_t)i * 4) =
            make_uint2(*reinterpret_cast<uint32_t*>(&h0), *reinterpret_cast<uint32_t*>(&h1));
    } else if (i < 1548800 + 36864) {         // w2p[kk][co][kl]
        const int j = i - 1548800;
        const int kk = j >> 11, rem = j & 2047;
        const int co = rem >> 5, kl = rem & 31;
        const int tap = kk >> 1, ci = (kk & 1) * 32 + kl;
        ws[W2P_OFF + j] = __float2half(w2[co * 576 + ci * 9 + tap]);
    } else if (i < 1548800 + 36864 + 73728) { // w3p[cp][kk][co][kl]
        const int j = i - (1548800 + 36864);
        const int cp = j / 36864, r = j % 36864;
        const int kk = r >> 11, rem = r & 2047;
        const int col = rem >> 5, kl = rem & 31;
        const int co = cp * 64 + col;
        const int tap = kk >> 1, ci = (kk & 1) * 32 + kl;
        ws[W3P_OFF + j] = __float2half(w3[co * 576 + ci * 9 + tap]);
    }
}

// act: 128-B rows (64 fp16), 16B-granule XOR on (row&7)
__device__ __forceinline__ int lds128(int row, int colByte) {
    return row * 128 + (colByte ^ ((row & 7) << 4));
}

__device__ __forceinline__ uint32_t pk2(float a, float b) {
    __half2 h = __floats2half2_rn(a, b);
    return *reinterpret_cast<uint32_t*>(&h);
}

// ---- frag load/MFMA macros: all register-array indices are compile-time ----
#define LDW(dst, kk)                                                            \
    do { _Pragma("unroll")                                                      \
        for (int ct_ = 0; ct_ < 4; ++ct_)                                       \
            dst[ct_] = *reinterpret_cast<const f16x8*>(                         \
                wbuf + (kk) * 4096 + (ct_ * 16 + l15) * 64 + g * 16);           \
    } while (0)

#define LDA2(dst, kk)                                                           \
    do { const int tap_ = (kk) >> 1;                                            \
        const int ro_ = (tap_ / 3) * 26 + (tap_ % 3);                           \
        const int cb_ = ((kk) & 1) * 64 + g * 16;                               \
        _Pragma("unroll")                                                       \
        for (int t_ = 0; t_ < 5; ++t_)                                          \
            if (t_ < npt2)                                                      \
                dst[t_] = *reinterpret_cast<const f16x8*>(                      \
                    act + lds128(rb2[t_] + ro_, cb_));                          \
    } while (0)

#define MM2(wv, av)                                                             \
    do { _Pragma("unroll")                                                      \
        for (int t_ = 0; t_ < 5; ++t_)                                          \
            if (t_ < npt2) { _Pragma("unroll")                                  \
                for (int ct_ = 0; ct_ < 4; ++ct_)                               \
                    acc2[t_][ct_] = __builtin_amdgcn_mfma_f32_16x16x32_f16(     \
                        wv[ct_], av[t_], acc2[t_][ct_], 0, 0, 0);               \
            }                                                                   \
    } while (0)

#define LDA3(dst, kk)                                                           \
    do { const int tap_ = (kk) >> 1;                                            \
        const int ro_ = (tap_ / 3) * 24 + (tap_ % 3);                           \
        const int cb_ = ((kk) & 1) * 64 + g * 16;                               \
        _Pragma("unroll")                                                       \
        for (int t_ = 0; t_ < 4; ++t_)                                          \
            dst[t_] = *reinterpret_cast<const f16x8*>(                          \
                act + lds128(rb3[t_] + ro_, cb_));                              \
    } while (0)

#define MM3(wv, av)                                                             \
    do { _Pragma("unroll")                                                      \
        for (int t_ = 0; t_ < 4; ++t_) { _Pragma("unroll")                      \
            for (int ct_ = 0; ct_ < 4; ++ct_)                                   \
                acc3[t_][ct_] = __builtin_amdgcn_mfma_f32_16x16x32_f16(         \
                    wv[ct_], av[t_], acc3[t_][ct_], 0, 0, 0);                   \
        }                                                                       \
    } while (0)

// ---------------- fused conv1 -> conv2 -> conv3, FULL-patch blocks ----------------
// LDS: act 676x128 (86528) | wbuf 73728 | patch 784 f32 (3136) = 163392 B, 1 block/CU.
// K-loops: register double-buffered (A/B frag sets) so kk+1 loads overlap kk MFMAs;
// compiler emits counted lgkmcnt instead of a full drain per iteration.
__global__ __launch_bounds__(512, 2)
void k_conv123(const float* __restrict__ x,
               const float* __restrict__ w1, const float* __restrict__ b1,
               const float* __restrict__ g1, const float* __restrict__ be1,
               const float* __restrict__ m1, const float* __restrict__ v1,
               const float* __restrict__ b2, const float* __restrict__ g2,
               const float* __restrict__ be2, const float* __restrict__ m2,
               const float* __restrict__ v2,
               const float* __restrict__ b3, const float* __restrict__ g3,
               const float* __restrict__ be3, const float* __restrict__ m3,
               const float* __restrict__ v3,
               __half* __restrict__ ws)
{
    extern __shared__ char smem[];
    char* act = smem;                                   // 86528 B
    char* wbuf = smem + 86528;                          // 73728 B
    float* patch = reinterpret_cast<float*>(smem + 160256);  // 784 f32

    const int p = blockIdx.x;
    const int tid = threadIdx.x, lane = tid & 63, wave = tid >> 6;
    const int l15 = lane & 15, g = lane >> 4;

    const __half* w2p = ws + W2P_OFF;
    const __half* w3p = ws + W3P_OFF;

    // ---- patchify + stage w2s
    {
        const int b = p / 9, r9 = p - b * 9, hb = r9 / 3, wb = r9 - hb * 3;
        const float* xb = x + (size_t)b * 7056 + hb * 28 * 84 + wb * 28;
        #pragma unroll
        for (int u = 0; u < 2; ++u) {
            const int i = tid + u * 512;
            if (i < 784) patch[i] = xb[(i / 28) * 84 + (i % 28)];
        }
    }
    {
        uint4 v[9];
        #pragma unroll
        for (int u = 0; u < 9; ++u)
            v[u] = *reinterpret_cast<const uint4*>(w2p + (size_t)(tid + u * 512) * 8);
        #pragma unroll
        for (int u = 0; u < 9; ++u)
            *reinterpret_cast<uint4*>(wbuf + (tid + u * 512) * 16) = v[u];
    }
    __syncthreads();

    // ---- conv1 (all 64 ch): act[pix 0..675][ci 64]
    {
        const int co = lane;
        float wr[9];
        #pragma unroll
        for (int t = 0; t < 9; ++t) wr[t] = w1[co * 9 + t];
        const float sc = g1[co] * rsqrtf(v1[co] + EPS);
        const float sh = be1[co] - (m1[co] - b1[co]) * sc;
        for (int pix = wave; pix < 676; pix += 8) {
            const int yy = pix / 26, xx = pix - yy * 26;
            const float* pp = patch + yy * 28 + xx;
            float a = 0.f;
            #pragma unroll
            for (int ky = 0; ky < 3; ++ky)
                #pragma unroll
                for (int kx = 0; kx < 3; ++kx)
                    a = fmaf(pp[ky * 28 + kx], wr[ky * 3 + kx], a);
            const float v = fmaxf(fmaf(a, sc, sh), 0.f);
            *reinterpret_cast<__half*>(act + lds128(pix, co * 2)) = __float2half(v);
        }
    }
    __syncthreads();

    // ---- conv2: M=576 -> 36 tiles; waves 0-3: 5, waves 4-7: 4
    const int npt2 = (wave < 4) ? 5 : 4;
    const int mt0 = (wave < 4) ? wave * 5 : 20 + (wave - 4) * 4;
    int rb2[5];
    #pragma unroll
    for (int t = 0; t < 5; ++t) {
        int mt = mt0 + t; if (mt > 35) mt = 35;
        const int m = mt * 16 + l15;
        const int yy = m / 24, xx = m - yy * 24;
        rb2[t] = yy * 26 + xx;
    }
    f32x4 acc2[5][4];
    #pragma unroll
    for (int t = 0; t < 5; ++t)
        #pragma unroll
        for (int ct = 0; ct < 4; ++ct) acc2[t][ct] = (f32x4)0.f;

    {
        f16x8 w2A[4], a2A[5], w2B[4], a2B[5];
        LDW(w2A, 0); LDA2(a2A, 0);
        #pragma unroll
        for (int kp = 0; kp < 9; ++kp) {
            LDW(w2B, 2 * kp + 1); LDA2(a2B, 2 * kp + 1);
            MM2(w2A, a2A);
            if (kp < 8) { LDW(w2A, 2 * kp + 2); LDA2(a2A, 2 * kp + 2); }
            MM2(w2B, a2B);
        }
    }
    __syncthreads();   // conv2 reads of act & wbuf done

    // ---- stage w3s-cp0 (issue loads first) + h2 epilogue -> act[pix 0..575][co 64]
    {
        uint4 v[9];
        #pragma unroll
        for (int u = 0; u < 9; ++u)
            v[u] = *reinterpret_cast<const uint4*>(w3p + (size_t)(tid + u * 512) * 8);

        #pragma unroll
        for (int ct = 0; ct < 4; ++ct) {
            const int co0 = ct * 16 + g * 4;
            const float4 gg = *reinterpret_cast<const float4*>(g2 + co0);
            const float4 vv = *reinterpret_cast<const float4*>(v2 + co0);
            const float4 bb = *reinterpret_cast<const float4*>(b2 + co0);
            const float4 mm = *reinterpret_cast<const float4*>(m2 + co0);
            const float4 ee = *reinterpret_cast<const float4*>(be2 + co0);
            float scv[4], shv[4];
            scv[0] = gg.x * rsqrtf(vv.x + EPS); shv[0] = ee.x - (mm.x - bb.x) * scv[0];
            scv[1] = gg.y * rsqrtf(vv.y + EPS); shv[1] = ee.y - (mm.y - bb.y) * scv[1];
            scv[2] = gg.z * rsqrtf(vv.z + EPS); shv[2] = ee.z - (mm.z - bb.z) * scv[2];
            scv[3] = gg.w * rsqrtf(vv.w + EPS); shv[3] = ee.w - (mm.w - bb.w) * scv[3];
            #pragma unroll
            for (int t = 0; t < 5; ++t) {
                const int m = (mt0 + t) * 16 + l15;
                if (t < npt2 && m < 576) {
                    float v0 = fmaxf(fmaf(acc2[t][ct][0], scv[0], shv[0]), 0.f);
                    float v1 = fmaxf(fmaf(acc2[t][ct][1], scv[1], shv[1]), 0.f);
                    float v2_ = fmaxf(fmaf(acc2[t][ct][2], scv[2], shv[2]), 0.f);
                    float v3_ = fmaxf(fmaf(acc2[t][ct][3], scv[3], shv[3]), 0.f);
                    *reinterpret_cast<uint2*>(act + lds128(m, ct * 32 + g * 8)) =
                        make_uint2(pk2(v0, v1), pk2(v2_, v3_));
                }
            }
        }
        #pragma unroll
        for (int u = 0; u < 9; ++u)
            *reinterpret_cast<uint4*>(wbuf + (tid + u * 512) * 16) = v[u];
    }
    __syncthreads();

    // ---- conv3: M=484 -> 32 tiles, 4/wave; two co-passes of 64
    int rb3[4];
    #pragma unroll
    for (int t = 0; t < 4; ++t) {
        int m = (wave * 4 + t) * 16 + l15;
        if (m > 483) m = 483;
        const int yy = m / 22, xx = m - yy * 22;
        rb3[t] = yy * 24 + xx;
    }
    __half* slot = ws + H3_OFF + (size_t)p * 61952;   // [co 128][pix 484]

    #pragma unroll
    for (int cp = 0; cp < 2; ++cp) {
        const int cb = cp * 64;
        f32x4 acc3[4][4];
        #pragma unroll
        for (int t = 0; t < 4; ++t)
            #pragma unroll
            for (int ct = 0; ct < 4; ++ct) acc3[t][ct] = (f32x4)0.f;

        {
            f16x8 w3A[4], a3A[4], w3B[4], a3B[4];
            LDW(w3A, 0); LDA3(a3A, 0);
            #pragma unroll
            for (int kp = 0; kp < 9; ++kp) {
                LDW(w3B, 2 * kp + 1); LDA3(a3B, 2 * kp + 1);
                MM3(w3A, a3A);
                if (kp < 8) { LDW(w3A, 2 * kp + 2); LDA3(a3A, 2 * kp + 2); }
                MM3(w3B, a3B);
            }
        }
        __syncthreads();   // cp reads of wbuf done (before cp1 restage)

        uint4 sv[9];
        if (cp == 0) {
            #pragma unroll
            for (int u = 0; u < 9; ++u)
                sv[u] = *reinterpret_cast<const uint4*>(
                    w3p + 36864 + (size_t)(tid + u * 512) * 8);
        }

        // epilogue: BN+ReLU -> h3[co][pix]
        #pragma unroll
        for (int ct = 0; ct < 4; ++ct) {
            const int co0 = cb + ct * 16 + g * 4;
            const float4 gg = *reinterpret_cast<const float4*>(g3 + co0);
            const float4 vv = *reinterpret_cast<const float4*>(v3 + co0);
            const float4 bb = *reinterpret_cast<const float4*>(b3 + co0);
            const float4 mm = *reinterpret_cast<const float4*>(m3 + co0);
            const float4 ee = *reinterpret_cast<const float4*>(be3 + co0);
            float scv[4], shv[4];
            scv[0] = gg.x * rsqrtf(vv.x + EPS); shv[0] = ee.x - (mm.x - bb.x) * scv[0];
            scv[1] = gg.y * rsqrtf(vv.y + EPS); shv[1] = ee.y - (mm.y - bb.y) * scv[1];
            scv[2] = gg.z * rsqrtf(vv.z + EPS); shv[2] = ee.z - (mm.z - bb.z) * scv[2];
            scv[3] = gg.w * rsqrtf(vv.w + EPS); shv[3] = ee.w - (mm.w - bb.w) * scv[3];
            #pragma unroll
            for (int t = 0; t < 4; ++t) {
                const int m = (wave * 4 + t) * 16 + l15;
                if (m < 484) {
                    slot[(size_t)(co0 + 0) * 484 + m] =
                        __float2half(fmaxf(fmaf(acc3[t][ct][0], scv[0], shv[0]), 0.f));
                    slot[(size_t)(co0 + 1) * 484 + m] =
                        __float2half(fmaxf(fmaf(acc3[t][ct][1], scv[1], shv[1]), 0.f));
                    slot[(size_t)(co0 + 2) * 484 + m] =
                        __float2half(fmaxf(fmaf(acc3[t][ct][2], scv[2], shv[2]), 0.f));
                    slot[(size_t)(co0 + 3) * 484 + m] =
                        __float2half(fmaxf(fmaf(acc3[t][ct][3], scv[3], shv[3]), 0.f));
                }
            }
        }

        if (cp == 0) {
            #pragma unroll
            for (int u = 0; u < 9; ++u)
                *reinterpret_cast<uint4*>(wbuf + (tid + u * 512) * 16) = sv[u];
            __syncthreads();
        }
    }
}

// ---------------- out = bias ----------------
__global__ void k_init(const float* __restrict__ bf, float* __restrict__ out)
{
    const int i = blockIdx.x * 256 + threadIdx.x;
    if (i < 115200) out[i] = bf[i % 100];
}

// ---------------- FC (MFMA): M-block=128 patches, 44 K-chunks, atomics ----------------
__global__ __launch_bounds__(512)
void k_fc(const __half* __restrict__ ws, float* __restrict__ out)
{
    const __half* h3 = ws + H3_OFF;
    const __half* wfh = ws + WFH_OFF;
    const int bid = blockIdx.x;            // 9 mb x 44 kc = 396
    const int mb = bid % 9, kc = bid / 9;
    const int tid = threadIdx.x, lane = tid & 63, wave = tid >> 6;
    const int wm = wave >> 1, wn = wave & 1;
    const int l15 = lane & 15, g = lane >> 4;

    const size_t kbase = (size_t)kc * 1408 + g * 8;
    const __half* Ap[2];
    #pragma unroll
    for (int mt = 0; mt < 2; ++mt) {
        const int patchm = mb * 128 + wm * 32 + mt * 16 + l15;
        Ap[mt] = h3 + (size_t)patchm * 61952 + kbase;
    }
    const __half* Bp[4];
    #pragma unroll
    for (int nt = 0; nt < 4; ++nt) {
        const int orow = wn * 64 + nt * 16 + l15;
        Bp[nt] = wfh + (size_t)orow * 61952 + kbase;
    }

    f32x4 acc[2][4];
    #pragma unroll
    for (int mt = 0; mt < 2; ++mt)
        #pragma unroll
        for (int nt = 0; nt < 4; ++nt) acc[mt][nt] = (f32x4)0.f;

    #pragma unroll 4
    for (int kk = 0; kk < 44; ++kk) {
        const f16x8 a0 = *reinterpret_cast<const f16x8*>(Ap[0] + kk * 32);
        const f16x8 a1 = *reinterpret_cast<const f16x8*>(Ap[1] + kk * 32);
        f16x8 b[4];
        #pragma unroll
        for (int nt = 0; nt < 4; ++nt)
            b[nt] = *reinterpret_cast<const f16x8*>(Bp[nt] + kk * 32);
        #pragma unroll
        for (int nt = 0; nt < 4; ++nt) {
            acc[0][nt] = __builtin_amdgcn_mfma_f32_16x16x32_f16(a0, b[nt], acc[0][nt], 0, 0, 0);
            acc[1][nt] = __builtin_amdgcn_mfma_f32_16x16x32_f16(a1, b[nt], acc[1][nt], 0, 0, 0);
        }
    }

    #pragma unroll
    for (int mt = 0; mt < 2; ++mt)
        #pragma unroll
        for (int nt = 0; nt < 4; ++nt) {
            const int col = wn * 64 + nt * 16 + l15;
            if (col < 100) {
                #pragma unroll
                for (int r = 0; r < 4; ++r) {
                    const int row = mb * 128 + wm * 32 + mt * 16 + g * 4 + r;
                    atomicAdd(out + (size_t)row * 100 + col, acc[mt][nt][r]);
                }
            }
        }
}

extern "C" void kernel_launch(void* const* d_in, const int* in_sizes, int n_in,
                              void* d_out, int out_size, void* d_ws, size_t ws_size,
                              hipStream_t stream)
{
    const float* x   = (const float*)d_in[0];
    const float* w1  = (const float*)d_in[1];
    const float* b1  = (const float*)d_in[2];
    const float* g1  = (const float*)d_in[3];
    const float* be1 = (const float*)d_in[4];
    const float* m1  = (const float*)d_in[5];
    const float* v1  = (const float*)d_in[6];
    const float* w2  = (const float*)d_in[7];
    const float* b2  = (const float*)d_in[8];
    const float* g2  = (const float*)d_in[9];
    const float* be2 = (const float*)d_in[10];
    const float* m2  = (const float*)d_in[11];
    const float* v2  = (const float*)d_in[12];
    const float* w3  = (const float*)d_in[13];
    const float* b3  = (const float*)d_in[14];
    const float* g3  = (const float*)d_in[15];
    const float* be3 = (const float*)d_in[16];
    const float* m3  = (const float*)d_in[17];
    const float* v3  = (const float*)d_in[18];
    const float* wf  = (const float*)d_in[19];
    const float* bf  = (const float*)d_in[20];

    __half* hws = (__half*)d_ws;     // 155,348,992 B
    float* out = (float*)d_out;

    hipFuncSetAttribute(reinterpret_cast<const void*>(k_conv123),
                        hipFuncAttributeMaxDynamicSharedMemorySize, 163392);

    k_prep<<<6483, 256, 0, stream>>>(w2, w3, wf, hws);
    k_conv123<<<1152, 512, 163392, stream>>>(x, w1, b1, g1, be1, m1, v1,
                                             b2, g2, be2, m2, v2,
                                             b3, g3, be3, m3, v3, hws);
    k_init<<<450, 256, 0, stream>>>(bf, out);
    k_fc<<<396, 512, 0, stream>>>(hws, out);
}

// Round 9
// 319.005 us; speedup vs baseline: 1.1772x; 1.1772x over previous
//
#include <hip/hip_runtime.h>
#include <hip/hip_fp16.h>

#define EPS 1e-5f

typedef _Float16 f16x8 __attribute__((ext_vector_type(8)));
typedef float f32x4 __attribute__((ext_vector_type(4)));

// ---- ws layout (halfs): 155,348,992 B ----
#define WFH_OFF 0ull
#define W2P_OFF 6195200ull          // [kk 18][co 64][kl 32]
#define W3P_OFF 6232064ull          // [wn 2][kk 18][co 64][kl 32]
#define H3_OFF  6305792ull          // 1152 x 61952, per patch [co 128][pix 484]

// ---------------- prep: weight repacks + output bias-init ----------------
__global__ __launch_bounds__(256)
void k_prep(const float* __restrict__ w2, const float* __restrict__ w3,
            const float* __restrict__ wf, const float* __restrict__ bf,
            __half* __restrict__ ws, float* __restrict__ out)
{
    const int i = blockIdx.x * 256 + threadIdx.x;
    if (i < 1548800) {                        // wfh: vectorized linear cast
        const float4 f = *reinterpret_cast<const float4*>(wf + (size_t)i * 4);
        __half2 h0 = __floats2half2_rn(f.x, f.y);
        __half2 h1 = __floats2half2_rn(f.z, f.w);
        *reinterpret_cast<uint2*>(ws + WFH_OFF + (size_t)i * 4) =
            make_uint2(*reinterpret_cast<uint32_t*>(&h0), *reinterpret_cast<uint32_t*>(&h1));
    } else if (i < 1585664) {                 // w2p[kk][co][kl]
        const int j = i - 1548800;
        const int kk = j >> 11, rem = j & 2047;
        const int co = rem >> 5, kl = rem & 31;
        const int tap = kk >> 1, ci = (kk & 1) * 32 + kl;
        ws[W2P_OFF + j] = __float2half(w2[co * 576 + ci * 9 + tap]);
    } else if (i < 1659392) {                 // w3p[wn][kk][co64][kl]
        const int j = i - 1585664;
        const int wn = j / 36864, r = j % 36864;
        const int kk = r >> 11, rem = r & 2047;
        const int col = rem >> 5, kl = rem & 31;
        const int co = wn * 64 + col;
        const int tap = kk >> 1, ci = (kk & 1) * 32 + kl;
        ws[W3P_OFF + j] = __float2half(w3[co * 576 + ci * 9 + tap]);
    } else if (i < 1774592) {                 // out = bias
        const int j = i - 1659392;
        out[j] = bf[j % 100];
    }
}

// act: 128-B rows (64 fp16), 16B-granule XOR on (row&7)
__device__ __forceinline__ int lds128(int row, int colByte) {
    return row * 128 + (colByte ^ ((row & 7) << 4));
}

__device__ __forceinline__ uint32_t pk2(float a, float b) {
    __half2 h = __floats2half2_rn(a, b);
    return *reinterpret_cast<uint32_t*>(&h);
}

// ---------------- fused conv1 -> conv2 -> conv3, half-patch blocks ----------------
// LDS: patch 476 f32 (1904 B) + act 390 x 128 B (49920 B) = 51824 B -> 3 blocks/CU,
// 24 waves/CU (6/SIMD). Weight frags read DIRECTLY from L2-resident global
// (w2p/w3p contiguous 1024 B per wave -- no gathers, no LDS weight buffer).
// Wave grid 4M x 2N for both convs (balanced). 4 barriers.
__global__ __launch_bounds__(512, 2)
void k_conv123(const float* __restrict__ x,
               const float* __restrict__ w1, const float* __restrict__ b1,
               const float* __restrict__ g1, const float* __restrict__ be1,
               const float* __restrict__ m1, const float* __restrict__ v1,
               const float* __restrict__ b2, const float* __restrict__ g2,
               const float* __restrict__ be2, const float* __restrict__ m2,
               const float* __restrict__ v2,
               const float* __restrict__ b3, const float* __restrict__ g3,
               const float* __restrict__ be3, const float* __restrict__ m3,
               const float* __restrict__ v3,
               __half* __restrict__ ws)
{
    __shared__ char smem[51824];
    float* patch = reinterpret_cast<float*>(smem);   // 476 f32
    char* act = smem + 1904;                         // 390 x 128 B (conv1-out / h2)

    const int bid = blockIdx.x;
    const int p = bid >> 1, half = bid & 1;
    const int tid = threadIdx.x, lane = tid & 63, wave = tid >> 6;
    const int l15 = lane & 15, g = lane >> 4;
    const int wm = wave >> 1, wn = wave & 1;      // 4 M-groups x 2 N-groups
    const int base3 = half * 11;

    // ---- patchify: x rows base3..base3+16 of this patch
    {
        const int b = p / 9, r9 = p - b * 9, hb = r9 / 3, wb = r9 - hb * 3;
        const float* xb = x + (size_t)b * 7056 + (hb * 28 + base3) * 84 + wb * 28;
        if (tid < 476) patch[tid] = xb[(tid / 28) * 84 + (tid % 28)];
    }
    __syncthreads();

    // ---- conv1 (all 64 ch): act[pix 0..389][ci 64]
    {
        const int co = lane;
        float wr[9];
        #pragma unroll
        for (int t = 0; t < 9; ++t) wr[t] = w1[co * 9 + t];
        const float sc = g1[co] * rsqrtf(v1[co] + EPS);
        const float sh = be1[co] - (m1[co] - b1[co]) * sc;
        for (int pix = wave; pix < 390; pix += 8) {
            const int yy = pix / 26, xx = pix - yy * 26;
            const float* pp = patch + yy * 28 + xx;    // wave-uniform -> broadcast
            float a = 0.f;
            #pragma unroll
            for (int ky = 0; ky < 3; ++ky)
                #pragma unroll
                for (int kx = 0; kx < 3; ++kx)
                    a = fmaf(pp[ky * 28 + kx], wr[ky * 3 + kx], a);
            const float v = fmaxf(fmaf(a, sc, sh), 0.f);
            *reinterpret_cast<__half*>(act + lds128(pix, co * 2)) = __float2half(v);
        }
    }
    __syncthreads();

    // ---- conv2: M=312 (13x24) -> 20 tiles (5/wm); N=64 -> 2 ct per wn. K=576.
    int rb2[5];
    #pragma unroll
    for (int t = 0; t < 5; ++t) {
        int m = (wm * 5 + t) * 16 + l15;
        if (m > 311) m = 311;
        const int yy = m / 24, xx = m - yy * 24;
        rb2[t] = yy * 26 + xx;
    }
    f32x4 acc2[5][2];
    #pragma unroll
    for (int t = 0; t < 5; ++t)
        #pragma unroll
        for (int ct = 0; ct < 2; ++ct) acc2[t][ct] = (f32x4)0.f;

    {
        const __half* w2w = ws + W2P_OFF + wn * 1024 + l15 * 32 + g * 8;
        #pragma unroll 3
        for (int kk = 0; kk < 18; ++kk) {
            const int tap = kk >> 1;
            const int ro = (tap / 3) * 26 + (tap % 3);
            const int cb = (kk & 1) * 64 + g * 16;
            f16x8 wf[2];
            wf[0] = *reinterpret_cast<const f16x8*>(w2w + kk * 2048);
            wf[1] = *reinterpret_cast<const f16x8*>(w2w + kk * 2048 + 512);
            f16x8 af[5];
            #pragma unroll
            for (int t = 0; t < 5; ++t)
                af[t] = *reinterpret_cast<const f16x8*>(act + lds128(rb2[t] + ro, cb));
            #pragma unroll
            for (int t = 0; t < 5; ++t)
                #pragma unroll
                for (int ct = 0; ct < 2; ++ct)
                    acc2[t][ct] = __builtin_amdgcn_mfma_f32_16x16x32_f16(
                        wf[ct], af[t], acc2[t][ct], 0, 0, 0);   // D: row=co, col=pix
        }
    }
    __syncthreads();   // conv2 reads of act done

    // ---- h2 epilogue: BN+ReLU -> act[pix 0..311][co 64] (aliased). acc2 dies.
    {
        #pragma unroll
        for (int ct = 0; ct < 2; ++ct) {
            const int co0 = wn * 32 + ct * 16 + g * 4;
            const float4 gg = *reinterpret_cast<const float4*>(g2 + co0);
            const float4 vv = *reinterpret_cast<const float4*>(v2 + co0);
            const float4 bb = *reinterpret_cast<const float4*>(b2 + co0);
            const float4 mm = *reinterpret_cast<const float4*>(m2 + co0);
            const float4 ee = *reinterpret_cast<const float4*>(be2 + co0);
            float scv[4], shv[4];
            scv[0] = gg.x * rsqrtf(vv.x + EPS); shv[0] = ee.x - (mm.x - bb.x) * scv[0];
            scv[1] = gg.y * rsqrtf(vv.y + EPS); shv[1] = ee.y - (mm.y - bb.y) * scv[1];
            scv[2] = gg.z * rsqrtf(vv.z + EPS); shv[2] = ee.z - (mm.z - bb.z) * scv[2];
            scv[3] = gg.w * rsqrtf(vv.w + EPS); shv[3] = ee.w - (mm.w - bb.w) * scv[3];
            #pragma unroll
            for (int t = 0; t < 5; ++t) {
                const int m = (wm * 5 + t) * 16 + l15;
                if (m < 312) {
                    float v0 = fmaxf(fmaf(acc2[t][ct][0], scv[0], shv[0]), 0.f);
                    float v1 = fmaxf(fmaf(acc2[t][ct][1], scv[1], shv[1]), 0.f);
                    float v2_ = fmaxf(fmaf(acc2[t][ct][2], scv[2], shv[2]), 0.f);
                    float v3_ = fmaxf(fmaf(acc2[t][ct][3], scv[3], shv[3]), 0.f);
                    *reinterpret_cast<uint2*>(
                        act + lds128(m, wn * 64 + ct * 32 + g * 8)) =
                        make_uint2(pk2(v0, v1), pk2(v2_, v3_));
                }
            }
        }
    }
    __syncthreads();

    // ---- conv3: M=242 (11x22) -> 16 tiles (4/wm); N=128 -> wn co-half, 4 ct. K=576.
    int rb3[4];
    #pragma unroll
    for (int t = 0; t < 4; ++t) {
        int m = (wm * 4 + t) * 16 + l15;
        if (m > 241) m = 241;
        const int yy = m / 22, xx = m - yy * 22;
        rb3[t] = yy * 24 + xx;
    }
    f32x4 acc3[4][4];
    #pragma unroll
    for (int t = 0; t < 4; ++t)
        #pragma unroll
        for (int ct = 0; ct < 4; ++ct) acc3[t][ct] = (f32x4)0.f;

    {
        const __half* w3w = ws + W3P_OFF + wn * 36864 + l15 * 32 + g * 8;
        #pragma unroll 3
        for (int kk = 0; kk < 18; ++kk) {
            const int tap = kk >> 1;
            const int ro = (tap / 3) * 24 + (tap % 3);
            const int cb = (kk & 1) * 64 + g * 16;
            f16x8 wf[4];
            #pragma unroll
            for (int ct = 0; ct < 4; ++ct)
                wf[ct] = *reinterpret_cast<const f16x8*>(w3w + kk * 2048 + ct * 512);
            f16x8 af[4];
            #pragma unroll
            for (int t = 0; t < 4; ++t)
                af[t] = *reinterpret_cast<const f16x8*>(act + lds128(rb3[t] + ro, cb));
            #pragma unroll
            for (int t = 0; t < 4; ++t)
                #pragma unroll
                for (int ct = 0; ct < 4; ++ct)
                    acc3[t][ct] = __builtin_amdgcn_mfma_f32_16x16x32_f16(
                        wf[ct], af[t], acc3[t][ct], 0, 0, 0);
        }
    }

    // ---- h3 epilogue: BN+ReLU -> h3[co 128][pix 484]
    {
        __half* slot = ws + H3_OFF + (size_t)p * 61952;
        #pragma unroll
        for (int ct = 0; ct < 4; ++ct) {
            const int co0 = wn * 64 + ct * 16 + g * 4;
            const float4 gg = *reinterpret_cast<const float4*>(g3 + co0);
            const float4 vv = *reinterpret_cast<const float4*>(v3 + co0);
            const float4 bb = *reinterpret_cast<const float4*>(b3 + co0);
            const float4 mm = *reinterpret_cast<const float4*>(m3 + co0);
            const float4 ee = *reinterpret_cast<const float4*>(be3 + co0);
            float scv[4], shv[4];
            scv[0] = gg.x * rsqrtf(vv.x + EPS); shv[0] = ee.x - (mm.x - bb.x) * scv[0];
            scv[1] = gg.y * rsqrtf(vv.y + EPS); shv[1] = ee.y - (mm.y - bb.y) * scv[1];
            scv[2] = gg.z * rsqrtf(vv.z + EPS); shv[2] = ee.z - (mm.z - bb.z) * scv[2];
            scv[3] = gg.w * rsqrtf(vv.w + EPS); shv[3] = ee.w - (mm.w - bb.w) * scv[3];
            #pragma unroll
            for (int t = 0; t < 4; ++t) {
                const int m = (wm * 4 + t) * 16 + l15;
                if (m < 242) {
                    const int pixg = 242 * half + m;
                    slot[(size_t)(co0 + 0) * 484 + pixg] =
                        __float2half(fmaxf(fmaf(acc3[t][ct][0], scv[0], shv[0]), 0.f));
                    slot[(size_t)(co0 + 1) * 484 + pixg] =
                        __float2half(fmaxf(fmaf(acc3[t][ct][1], scv[1], shv[1]), 0.f));
                    slot[(size_t)(co0 + 2) * 484 + pixg] =
                        __float2half(fmaxf(fmaf(acc3[t][ct][2], scv[2], shv[2]), 0.f));
                    slot[(size_t)(co0 + 3) * 484 + pixg] =
                        __float2half(fmaxf(fmaf(acc3[t][ct][3], scv[3], shv[3]), 0.f));
                }
            }
        }
    }
}

// ---------------- FC (MFMA): M-block=128 patches, 44 K-chunks, atomics ----------------
__global__ __launch_bounds__(512)
void k_fc(const __half* __restrict__ ws, float* __restrict__ out)
{
    const __half* h3 = ws + H3_OFF;
    const __half* wfh = ws + WFH_OFF;
    const int bid = blockIdx.x;            // 9 mb x 44 kc = 396
    const int mb = bid % 9, kc = bid / 9;
    const int tid = threadIdx.x, lane = tid & 63, wave = tid >> 6;
    const int wm = wave >> 1, wn = wave & 1;
    const int l15 = lane & 15, g = lane >> 4;

    const size_t kbase = (size_t)kc * 1408 + g * 8;
    const __half* Ap[2];
    #pragma unroll
    for (int mt = 0; mt < 2; ++mt) {
        const int patchm = mb * 128 + wm * 32 + mt * 16 + l15;
        Ap[mt] = h3 + (size_t)patchm * 61952 + kbase;
    }
    const __half* Bp[4];
    #pragma unroll
    for (int nt = 0; nt < 4; ++nt) {
        const int orow = wn * 64 + nt * 16 + l15;
        Bp[nt] = wfh + (size_t)orow * 61952 + kbase;
    }

    f32x4 acc[2][4];
    #pragma unroll
    for (int mt = 0; mt < 2; ++mt)
        #pragma unroll
        for (int nt = 0; nt < 4; ++nt) acc[mt][nt] = (f32x4)0.f;

    #pragma unroll 4
    for (int kk = 0; kk < 44; ++kk) {
        const f16x8 a0 = *reinterpret_cast<const f16x8*>(Ap[0] + kk * 32);
        const f16x8 a1 = *reinterpret_cast<const f16x8*>(Ap[1] + kk * 32);
        f16x8 b[4];
        #pragma unroll
        for (int nt = 0; nt < 4; ++nt)
            b[nt] = *reinterpret_cast<const f16x8*>(Bp[nt] + kk * 32);
        #pragma unroll
        for (int nt = 0; nt < 4; ++nt) {
            acc[0][nt] = __builtin_amdgcn_mfma_f32_16x16x32_f16(a0, b[nt], acc[0][nt], 0, 0, 0);
            acc[1][nt] = __builtin_amdgcn_mfma_f32_16x16x32_f16(a1, b[nt], acc[1][nt], 0, 0, 0);
        }
    }

    #pragma unroll
    for (int mt = 0; mt < 2; ++mt)
        #pragma unroll
        for (int nt = 0; nt < 4; ++nt) {
            const int col = wn * 64 + nt * 16 + l15;
            if (col < 100) {
                #pragma unroll
                for (int r = 0; r < 4; ++r) {
                    const int row = mb * 128 + wm * 32 + mt * 16 + g * 4 + r;
                    atomicAdd(out + (size_t)row * 100 + col, acc[mt][nt][r]);
                }
            }
        }
}

extern "C" void kernel_launch(void* const* d_in, const int* in_sizes, int n_in,
                              void* d_out, int out_size, void* d_ws, size_t ws_size,
                              hipStream_t stream)
{
    const float* x   = (const float*)d_in[0];
    const float* w1  = (const float*)d_in[1];
    const float* b1  = (const float*)d_in[2];
    const float* g1  = (const float*)d_in[3];
    const float* be1 = (const float*)d_in[4];
    const float* m1  = (const float*)d_in[5];
    const float* v1  = (const float*)d_in[6];
    const float* w2  = (const float*)d_in[7];
    const float* b2  = (const float*)d_in[8];
    const float* g2  = (const float*)d_in[9];
    const float* be2 = (const float*)d_in[10];
    const float* m2  = (const float*)d_in[11];
    const float* v2  = (const float*)d_in[12];
    const float* w3  = (const float*)d_in[13];
    const float* b3  = (const float*)d_in[14];
    const float* g3  = (const float*)d_in[15];
    const float* be3 = (const float*)d_in[16];
    const float* m3  = (const float*)d_in[17];
    const float* v3  = (const float*)d_in[18];
    const float* wf  = (const float*)d_in[19];
    const float* bf  = (const float*)d_in[20];

    __half* hws = (__half*)d_ws;     // 155,348,992 B
    float* out = (float*)d_out;

    k_prep<<<6932, 256, 0, stream>>>(w2, w3, wf, bf, hws, out);
    k_conv123<<<2304, 512, 0, stream>>>(x, w1, b1, g1, be1, m1, v1,
                                        b2, g2, be2, m2, v2,
                                        b3, g3, be3, m3, v3, hws);
    k_fc<<<396, 512, 0, stream>>>(hws, out);
}

// Round 10
// 298.254 us; speedup vs baseline: 1.2591x; 1.0696x over previous
//
#include <hip/hip_runtime.h>
#include <hip/hip_fp16.h>

#define EPS 1e-5f

typedef _Float16 f16x8 __attribute__((ext_vector_type(8)));
typedef float f32x4 __attribute__((ext_vector_type(4)));

// ---- ws layout (halfs): 155,352,320 B ----
#define WFH_OFF 0ull
#define W2P_OFF 6195200ull          // [kk 18][co 64][kl 32], pre-scaled by BN
#define W3P_OFF 6232064ull          // [wn 2][kk 18][co 64][kl 32], pre-scaled
#define H3_OFF  6305792ull          // 1152 x 61952, per patch [co 128][pix 484]
#define FOLD_OFF 77674496ull        // float region: [0,576) w1f | [576,640) sh1
                                    // | [640,704) sh2 | [704,832) sh3

// ---------------- prep: weight repacks (BN-folded) + bias-init ----------------
__global__ __launch_bounds__(256)
void k_prep(const float* __restrict__ w1, const float* __restrict__ b1,
            const float* __restrict__ g1, const float* __restrict__ be1,
            const float* __restrict__ m1, const float* __restrict__ v1,
            const float* __restrict__ w2, const float* __restrict__ b2,
            const float* __restrict__ g2, const float* __restrict__ be2,
            const float* __restrict__ m2, const float* __restrict__ v2,
            const float* __restrict__ w3, const float* __restrict__ b3,
            const float* __restrict__ g3, const float* __restrict__ be3,
            const float* __restrict__ m3, const float* __restrict__ v3,
            const float* __restrict__ wf, const float* __restrict__ bf,
            __half* __restrict__ ws, float* __restrict__ out)
{
    const int i = blockIdx.x * 256 + threadIdx.x;
    float* fold = reinterpret_cast<float*>(ws + FOLD_OFF);
    if (i < 1548800) {                        // wfh: vectorized linear cast
        const float4 f = *reinterpret_cast<const float4*>(wf + (size_t)i * 4);
        __half2 h0 = __floats2half2_rn(f.x, f.y);
        __half2 h1 = __floats2half2_rn(f.z, f.w);
        *reinterpret_cast<uint2*>(ws + WFH_OFF + (size_t)i * 4) =
            make_uint2(*reinterpret_cast<uint32_t*>(&h0), *reinterpret_cast<uint32_t*>(&h1));
    } else if (i < 1585664) {                 // w2p[kk][co][kl] * sc2[co]
        const int j = i - 1548800;
        const int kk = j >> 11, rem = j & 2047;
        const int co = rem >> 5, kl = rem & 31;
        const int tap = kk >> 1, ci = (kk & 1) * 32 + kl;
        const float sc = g2[co] * rsqrtf(v2[co] + EPS);
        ws[W2P_OFF + j] = __float2half(w2[co * 576 + ci * 9 + tap] * sc);
    } else if (i < 1659392) {                 // w3p[wn][kk][co64][kl] * sc3[co]
        const int j = i - 1585664;
        const int wn = j / 36864, r = j % 36864;
        const int kk = r >> 11, rem = r & 2047;
        const int col = rem >> 5, kl = rem & 31;
        const int co = wn * 64 + col;
        const int tap = kk >> 1, ci = (kk & 1) * 32 + kl;
        const float sc = g3[co] * rsqrtf(v3[co] + EPS);
        ws[W3P_OFF + j] = __float2half(w3[co * 576 + ci * 9 + tap] * sc);
    } else if (i < 1774592) {                 // out = bias
        const int j = i - 1659392;
        out[j] = bf[j % 100];
    } else if (i < 1775424) {                 // fold region
        const int j = i - 1774592;
        if (j < 576) {
            const int co = j / 9;
            fold[j] = w1[j] * (g1[co] * rsqrtf(v1[co] + EPS));
        } else if (j < 640) {
            const int co = j - 576;
            const float sc = g1[co] * rsqrtf(v1[co] + EPS);
            fold[j] = be1[co] - (m1[co] - b1[co]) * sc;
        } else if (j < 704) {
            const int co = j - 640;
            const float sc = g2[co] * rsqrtf(v2[co] + EPS);
            fold[j] = be2[co] - (m2[co] - b2[co]) * sc;
        } else {
            const int co = j - 704;
            const float sc = g3[co] * rsqrtf(v3[co] + EPS);
            fold[j] = be3[co] - (m3[co] - b3[co]) * sc;
        }
    }
}

// act: 128-B rows (64 fp16), 16B-granule XOR on (row&7)
__device__ __forceinline__ int lds128(int row, int colByte) {
    return row * 128 + (colByte ^ ((row & 7) << 4));
}

__device__ __forceinline__ uint32_t pk2(float a, float b) {
    __half2 h = __floats2half2_rn(a, b);
    return *reinterpret_cast<uint32_t*>(&h);
}

// ---------------- fused conv1 -> conv2 -> conv3, half-patch blocks ----------------
// LDS 51824 B -> 3 blocks/CU. conv1: sliding-window rows (3 ds_read_b64 per 2 px,
// was 18 ds_read_b32 -- conv1 was ~77us/CU of pure LDS-pipe time in R9).
// K-loops: tap-outer, swizzled addrs computed once per tap; ci-half parity = addr^64.
__global__ __launch_bounds__(512, 2)
void k_conv123(const float* __restrict__ x, const __half* __restrict__ ws_c,
               __half* __restrict__ ws)
{
    __shared__ char smem[51824];
    float* patch = reinterpret_cast<float*>(smem);   // 476 f32
    char* act = smem + 1904;                         // 390 x 128 B

    const int bid = blockIdx.x;
    const int p = bid >> 1, half = bid & 1;
    const int tid = threadIdx.x, lane = tid & 63, wave = tid >> 6;
    const int l15 = lane & 15, g = lane >> 4;
    const int wm = wave >> 1, wn = wave & 1;
    const int base3 = half * 11;
    const float* fold = reinterpret_cast<const float*>(ws_c + FOLD_OFF);

    // ---- patchify: x rows base3..base3+16 of this patch
    {
        const int b = p / 9, r9 = p - b * 9, hb = r9 / 3, wb = r9 - hb * 3;
        const float* xb = x + (size_t)b * 7056 + (hb * 28 + base3) * 84 + wb * 28;
        if (tid < 476) patch[tid] = xb[(tid / 28) * 84 + (tid % 28)];
    }
    __syncthreads();

    // ---- conv1: wave owns rows {2w, 2w+1} of 15; sliding 3x3 window, float2 feeds
    {
        const int co = lane;
        float wr[9];
        #pragma unroll
        for (int t = 0; t < 9; ++t) wr[t] = fold[co * 9 + t];
        const float sh = fold[576 + co];
        #pragma unroll
        for (int rr = 0; rr < 2; ++rr) {
            const int r = wave * 2 + rr;
            if (r < 15) {
                const float* prow = patch + r * 28;
                float a0 = prow[0], a1 = prow[28], a2 = prow[56];
                float b0 = prow[1], b1 = prow[29], b2 = prow[57];
                for (int xp = 0; xp < 13; ++xp) {
                    const int xx = xp * 2;
                    const float2 c0 = *reinterpret_cast<const float2*>(prow + xx + 2);
                    const float2 c1 = *reinterpret_cast<const float2*>(prow + xx + 30);
                    const float2 c2 = *reinterpret_cast<const float2*>(prow + xx + 58);
                    float s = a0 * wr[0] + b0 * wr[1] + c0.x * wr[2]
                            + a1 * wr[3] + b1 * wr[4] + c1.x * wr[5]
                            + a2 * wr[6] + b2 * wr[7] + c2.x * wr[8];
                    *reinterpret_cast<__half*>(act + lds128(r * 26 + xx, co * 2)) =
                        __float2half(fmaxf(s + sh, 0.f));
                    s = b0 * wr[0] + c0.x * wr[1] + c0.y * wr[2]
                      + b1 * wr[3] + c1.x * wr[4] + c1.y * wr[5]
                      + b2 * wr[6] + c2.x * wr[7] + c2.y * wr[8];
                    *reinterpret_cast<__half*>(act + lds128(r * 26 + xx + 1, co * 2)) =
                        __float2half(fmaxf(s + sh, 0.f));
                    a0 = c0.x; a1 = c1.x; a2 = c2.x;
                    b0 = c0.y; b1 = c1.y; b2 = c2.y;
                }
            }
        }
    }
    __syncthreads();

    // ---- conv2: M=312 -> 20 tiles (5/wm); N=64 -> 2 ct per wn. K=576.
    int rb2[5];
    #pragma unroll
    for (int t = 0; t < 5; ++t) {
        int m = (wm * 5 + t) * 16 + l15;
        if (m > 311) m = 311;
        const int yy = m / 24, xx = m - yy * 24;
        rb2[t] = yy * 26 + xx;
    }
    f32x4 acc2[5][2];
    #pragma unroll
    for (int t = 0; t < 5; ++t)
        #pragma unroll
        for (int ct = 0; ct < 2; ++ct) acc2[t][ct] = (f32x4)0.f;

    {
        const __half* w2w = ws_c + W2P_OFF + wn * 1024 + l15 * 32 + g * 8;
        #pragma unroll
        for (int tap = 0; tap < 9; ++tap) {
            const int ro = (tap / 3) * 26 + (tap % 3);
            int ad[5];
            #pragma unroll
            for (int t = 0; t < 5; ++t) ad[t] = lds128(rb2[t] + ro, g * 16);
            #pragma unroll
            for (int par = 0; par < 2; ++par) {
                const int kk = tap * 2 + par;
                const f16x8 wv0 = *reinterpret_cast<const f16x8*>(w2w + kk * 2048);
                const f16x8 wv1 = *reinterpret_cast<const f16x8*>(w2w + kk * 2048 + 512);
                #pragma unroll
                for (int t = 0; t < 5; ++t) {
                    const f16x8 af = *reinterpret_cast<const f16x8*>(act + (ad[t] ^ (par * 64)));
                    acc2[t][0] = __builtin_amdgcn_mfma_f32_16x16x32_f16(wv0, af, acc2[t][0], 0, 0, 0);
                    acc2[t][1] = __builtin_amdgcn_mfma_f32_16x16x32_f16(wv1, af, acc2[t][1], 0, 0, 0);
                }
            }
        }
    }
    __syncthreads();   // conv2 reads of act done

    // ---- h2 epilogue: relu(acc + sh2) -> act[pix][co 64] (aliased). acc2 dies.
    {
        #pragma unroll
        for (int ct = 0; ct < 2; ++ct) {
            const int co0 = wn * 32 + ct * 16 + g * 4;
            const float4 sh4 = *reinterpret_cast<const float4*>(fold + 640 + co0);
            #pragma unroll
            for (int t = 0; t < 5; ++t) {
                const int m = (wm * 5 + t) * 16 + l15;
                if (m < 312) {
                    const float v0 = fmaxf(acc2[t][ct][0] + sh4.x, 0.f);
                    const float v1 = fmaxf(acc2[t][ct][1] + sh4.y, 0.f);
                    const float v2_ = fmaxf(acc2[t][ct][2] + sh4.z, 0.f);
                    const float v3_ = fmaxf(acc2[t][ct][3] + sh4.w, 0.f);
                    *reinterpret_cast<uint2*>(
                        act + lds128(m, wn * 64 + ct * 32 + g * 8)) =
                        make_uint2(pk2(v0, v1), pk2(v2_, v3_));
                }
            }
        }
    }
    __syncthreads();

    // ---- conv3: M=242 -> 16 tiles (4/wm); N=128 -> wn co-half, 4 ct. K=576.
    int rb3[4];
    #pragma unroll
    for (int t = 0; t < 4; ++t) {
        int m = (wm * 4 + t) * 16 + l15;
        if (m > 241) m = 241;
        const int yy = m / 22, xx = m - yy * 22;
        rb3[t] = yy * 24 + xx;
    }
    f32x4 acc3[4][4];
    #pragma unroll
    for (int t = 0; t < 4; ++t)
        #pragma unroll
        for (int ct = 0; ct < 4; ++ct) acc3[t][ct] = (f32x4)0.f;

    {
        const __half* w3w = ws_c + W3P_OFF + wn * 36864 + l15 * 32 + g * 8;
        #pragma unroll
        for (int tap = 0; tap < 9; ++tap) {
            const int ro = (tap / 3) * 24 + (tap % 3);
            int ad[4];
            #pragma unroll
            for (int t = 0; t < 4; ++t) ad[t] = lds128(rb3[t] + ro, g * 16);
            #pragma unroll
            for (int par = 0; par < 2; ++par) {
                const int kk = tap * 2 + par;
                f16x8 wv[4];
                #pragma unroll
                for (int ct = 0; ct < 4; ++ct)
                    wv[ct] = *reinterpret_cast<const f16x8*>(w3w + kk * 2048 + ct * 512);
                #pragma unroll
                for (int t = 0; t < 4; ++t) {
                    const f16x8 af = *reinterpret_cast<const f16x8*>(act + (ad[t] ^ (par * 64)));
                    #pragma unroll
                    for (int ct = 0; ct < 4; ++ct)
                        acc3[t][ct] = __builtin_amdgcn_mfma_f32_16x16x32_f16(
                            wv[ct], af, acc3[t][ct], 0, 0, 0);
                }
            }
        }
    }

    // ---- h3 epilogue: relu(acc + sh3) -> h3[co 128][pix 484]
    {
        __half* slot = ws + H3_OFF + (size_t)p * 61952;
        #pragma unroll
        for (int ct = 0; ct < 4; ++ct) {
            const int co0 = wn * 64 + ct * 16 + g * 4;
            const float4 sh4 = *reinterpret_cast<const float4*>(fold + 704 + co0);
            #pragma unroll
            for (int t = 0; t < 4; ++t) {
                const int m = (wm * 4 + t) * 16 + l15;
                if (m < 242) {
                    const int pixg = 242 * half + m;
                    slot[(size_t)(co0 + 0) * 484 + pixg] =
                        __float2half(fmaxf(acc3[t][ct][0] + sh4.x, 0.f));
                    slot[(size_t)(co0 + 1) * 484 + pixg] =
                        __float2half(fmaxf(acc3[t][ct][1] + sh4.y, 0.f));
                    slot[(size_t)(co0 + 2) * 484 + pixg] =
                        __float2half(fmaxf(acc3[t][ct][2] + sh4.z, 0.f));
                    slot[(size_t)(co0 + 3) * 484 + pixg] =
                        __float2half(fmaxf(acc3[t][ct][3] + sh4.w, 0.f));
                }
            }
        }
    }
}

// ---------------- FC (MFMA): M-block=128 patches, 44 K-chunks, atomics ----------------
__global__ __launch_bounds__(512)
void k_fc(const __half* __restrict__ ws, float* __restrict__ out)
{
    const __half* h3 = ws + H3_OFF;
    const __half* wfh = ws + WFH_OFF;
    const int bid = blockIdx.x;            // 9 mb x 44 kc = 396
    const int mb = bid % 9, kc = bid / 9;
    const int tid = threadIdx.x, lane = tid & 63, wave = tid >> 6;
    const int wm = wave >> 1, wn = wave & 1;
    const int l15 = lane & 15, g = lane >> 4;

    const size_t kbase = (size_t)kc * 1408 + g * 8;
    const __half* Ap[2];
    #pragma unroll
    for (int mt = 0; mt < 2; ++mt) {
        const int patchm = mb * 128 + wm * 32 + mt * 16 + l15;
        Ap[mt] = h3 + (size_t)patchm * 61952 + kbase;
    }
    const __half* Bp[4];
    #pragma unroll
    for (int nt = 0; nt < 4; ++nt) {
        const int orow = wn * 64 + nt * 16 + l15;
        Bp[nt] = wfh + (size_t)orow * 61952 + kbase;
    }

    f32x4 acc[2][4];
    #pragma unroll
    for (int mt = 0; mt < 2; ++mt)
        #pragma unroll
        for (int nt = 0; nt < 4; ++nt) acc[mt][nt] = (f32x4)0.f;

    #pragma unroll 4
    for (int kk = 0; kk < 44; ++kk) {
        const f16x8 a0 = *reinterpret_cast<const f16x8*>(Ap[0] + kk * 32);
        const f16x8 a1 = *reinterpret_cast<const f16x8*>(Ap[1] + kk * 32);
        f16x8 b[4];
        #pragma unroll
        for (int nt = 0; nt < 4; ++nt)
            b[nt] = *reinterpret_cast<const f16x8*>(Bp[nt] + kk * 32);
        #pragma unroll
        for (int nt = 0; nt < 4; ++nt) {
            acc[0][nt] = __builtin_amdgcn_mfma_f32_16x16x32_f16(a0, b[nt], acc[0][nt], 0, 0, 0);
            acc[1][nt] = __builtin_amdgcn_mfma_f32_16x16x32_f16(a1, b[nt], acc[1][nt], 0, 0, 0);
        }
    }

    #pragma unroll
    for (int mt = 0; mt < 2; ++mt)
        #pragma unroll
        for (int nt = 0; nt < 4; ++nt) {
            const int col = wn * 64 + nt * 16 + l15;
            if (col < 100) {
                #pragma unroll
                for (int r = 0; r < 4; ++r) {
                    const int row = mb * 128 + wm * 32 + mt * 16 + g * 4 + r;
                    atomicAdd(out + (size_t)row * 100 + col, acc[mt][nt][r]);
                }
            }
        }
}

extern "C" void kernel_launch(void* const* d_in, const int* in_sizes, int n_in,
                              void* d_out, int out_size, void* d_ws, size_t ws_size,
                              hipStream_t stream)
{
    const float* x   = (const float*)d_in[0];
    const float* w1  = (const float*)d_in[1];
    const float* b1  = (const float*)d_in[2];
    const float* g1  = (const float*)d_in[3];
    const float* be1 = (const float*)d_in[4];
    const float* m1  = (const float*)d_in[5];
    const float* v1  = (const float*)d_in[6];
    const float* w2  = (const float*)d_in[7];
    const float* b2  = (const float*)d_in[8];
    const float* g2  = (const float*)d_in[9];
    const float* be2 = (const float*)d_in[10];
    const float* m2  = (const float*)d_in[11];
    const float* v2  = (const float*)d_in[12];
    const float* w3  = (const float*)d_in[13];
    const float* b3  = (const float*)d_in[14];
    const float* g3  = (const float*)d_in[15];
    const float* be3 = (const float*)d_in[16];
    const float* m3  = (const float*)d_in[17];
    const float* v3  = (const float*)d_in[18];
    const float* wf  = (const float*)d_in[19];
    const float* bf  = (const float*)d_in[20];

    __half* hws = (__half*)d_ws;     // 155,352,320 B
    float* out = (float*)d_out;

    k_prep<<<6936, 256, 0, stream>>>(w1, b1, g1, be1, m1, v1,
                                     w2, b2, g2, be2, m2, v2,
                                     w3, b3, g3, be3, m3, v3,
                                     wf, bf, hws, out);
    k_conv123<<<2304, 512, 0, stream>>>(x, hws, hws);
    k_fc<<<396, 512, 0, stream>>>(hws, out);
}